// Round 3
// 686.932 us; speedup vs baseline: 1.0348x; 1.0348x over previous
//
#include <hip/hip_runtime.h>
#include <hip/hip_bf16.h>

// NonLinearReadoutBlock: out = silu((x@W1)/16) masked-by-head @ W2/sqrt(128)
// N=500000, D_IN=256, D_HID=128, NUM_HEADS=4, D_OUT=4
//
// v4: v2 (harness-verified, 710us) + LDS staging of W1p. No inline asm.
//  1. W1p staged in LDS in two 32 KB halves per block (was: every wave
//     re-reads all 64 KB of W1p from global -> 2 KB/row of B VMEM vs
//     1 KB/row of x). B now flows through LDS (conflict-free contiguous
//     ds_read_b128), VMEM instrs/wave 96 -> 40.
//  2. fp32->bf16 pack via __float2bfloat16 (RNE; compiler fuses pairs
//     into v_cvt_pk_bf16_f32 per m240 guidance — no hand-written asm).

#define D_IN   256
#define TILE_M 128   // 4 waves x 32 rows

typedef __attribute__((ext_vector_type(8))) short  short8;
typedef __attribute__((ext_vector_type(4))) float  float4v;
typedef __attribute__((ext_vector_type(4))) int    int4v;

__device__ __forceinline__ unsigned short f2bf_rne(float f) {
    union { float f; unsigned int u; } cv; cv.f = f;
    unsigned int u = cv.u;
    return (unsigned short)((u + 0x7FFFu + ((u >> 16) & 1u)) >> 16);
}

__device__ __forceinline__ short8 pack8(float4v lo, float4v hi) {
    short8 r;
    r[0] = (short)__bfloat16_as_ushort(__float2bfloat16(lo[0]));
    r[1] = (short)__bfloat16_as_ushort(__float2bfloat16(lo[1]));
    r[2] = (short)__bfloat16_as_ushort(__float2bfloat16(lo[2]));
    r[3] = (short)__bfloat16_as_ushort(__float2bfloat16(lo[3]));
    r[4] = (short)__bfloat16_as_ushort(__float2bfloat16(hi[0]));
    r[5] = (short)__bfloat16_as_ushort(__float2bfloat16(hi[1]));
    r[6] = (short)__bfloat16_as_ushort(__float2bfloat16(hi[2]));
    r[7] = (short)__bfloat16_as_ushort(__float2bfloat16(hi[3]));
    return r;
}

// ---------------- prep: W1 [256][128] fp32 -> fragment-ordered bf16, *1/16 ----------------
// B-frag layout for mfma_f32_16x16x32_bf16: lane holds B[k][n], n=lane&15, k=(lane>>4)*8+j.
// W1p[((kt*8+nt)*64 + lane)*8 + j]  (kt = k/32, nt = n/16)
__global__ void prep_w1(const float* __restrict__ W1, unsigned short* __restrict__ W1p) {
    int idx = blockIdx.x * 256 + threadIdx.x;   // 0..32767
    int i = idx >> 7;     // k: 0..255
    int j = idx & 127;    // n: 0..127
    unsigned short b = f2bf_rne(W1[idx] * 0.0625f);   // fold 1/sqrt(256)
    int kt = i >> 5, q = (i >> 3) & 3, jj = i & 7;
    int nt = j >> 4, mm = j & 15;
    int lane = q * 16 + mm;
    W1p[(((kt * 8 + nt) * 64 + lane) << 3) + jj] = b;
}

// ---------------- main fused kernel ----------------
__global__ __launch_bounds__(256)
void readout_v4(const float* __restrict__ x,
                const unsigned short* __restrict__ W1p,
                const float* __restrict__ W2,
                const int* __restrict__ heads,
                float* __restrict__ out, int nrows) {
    __shared__ unsigned short sB[16384];   // 32 KB: B-frags for 4 k-steps (half of W1p)

    const int t    = threadIdx.x;
    const int w    = t >> 6;          // wave id
    const int lane = t & 63;
    const int q    = lane >> 4;
    const int m    = lane & 15;
    const int rowbase = blockIdx.x * TILE_M + w * 32;   // wave's first row

    // A-frag row pointers (clamped; invalid rows masked at store)
    const int r0 = min(rowbase + m,      nrows - 1);
    const int r1 = min(rowbase + 16 + m, nrows - 1);
    const float* xr0 = x + (size_t)r0 * D_IN + q * 8;
    const float* xr1 = x + (size_t)r1 * D_IN + q * 8;
    const unsigned short* sbase = sB + lane * 8;

    float4v acc[2][8];   // [rowtile][nt]
    #pragma unroll
    for (int rt = 0; rt < 2; ++rt)
        #pragma unroll
        for (int nt = 0; nt < 8; ++nt) acc[rt][nt] = (float4v){0.f, 0.f, 0.f, 0.f};

    // ---- two phases: stage 32 KB of W1p in LDS, then 4 k-steps of k=32 ----
    #pragma unroll
    for (int p = 0; p < 2; ++p) {
        if (p) __syncthreads();   // all waves done reading phase-0 LDS
        {   // stage: 32 KB / 256 threads = 128 B/thread (8 x 16 B)
            const unsigned short* gsrc = W1p + p * 16384 + t * 8;
            float4v v[8];
            #pragma unroll
            for (int i = 0; i < 8; ++i)
                v[i] = *(const float4v*)(gsrc + i * 2048);
            #pragma unroll
            for (int i = 0; i < 8; ++i)
                *(float4v*)(sB + t * 8 + i * 2048) = v[i];
        }
        __syncthreads();

        #pragma unroll
        for (int ktl = 0; ktl < 4; ++ktl) {
            const int kt = p * 4 + ktl;
            float4v a0lo = *(const float4v*)(xr0 + kt * 32);
            float4v a0hi = *(const float4v*)(xr0 + kt * 32 + 4);
            float4v a1lo = *(const float4v*)(xr1 + kt * 32);
            float4v a1hi = *(const float4v*)(xr1 + kt * 32 + 4);
            short8 b[8];
            #pragma unroll
            for (int nt = 0; nt < 8; ++nt)
                b[nt] = *(const short8*)(sbase + (ktl * 8 + nt) * 512);
            short8 a0 = pack8(a0lo, a0hi);
            short8 a1 = pack8(a1lo, a1hi);
            #pragma unroll
            for (int nt = 0; nt < 8; ++nt) {
                acc[0][nt] = __builtin_amdgcn_mfma_f32_16x16x32_bf16(a0, b[nt], acc[0][nt], 0, 0, 0);
                acc[1][nt] = __builtin_amdgcn_mfma_f32_16x16x32_bf16(a1, b[nt], acc[1][nt], 0, 0, 0);
            }
        }
    }

    // ---- epilogue: head select + silu + W2 + 16-lane reduce, all in regs ----
    // D layout: col = nt*16 + m, row (in 16) = q*4 + reg
    const float sc = 0.08838834764831845f;   // 1/sqrt(128)
    const bool full = (rowbase + 32) <= nrows;  // wave-uniform
    #pragma unroll
    for (int rt = 0; rt < 2; ++rt) {
        int4v hv;
        if (full) {
            hv = *(const int4v*)(heads + rowbase + rt * 16 + q * 4);
        } else {
            #pragma unroll
            for (int e = 0; e < 4; ++e)
                hv[e] = heads[min(rowbase + rt * 16 + q * 4 + e, nrows - 1)];
        }
        #pragma unroll
        for (int reg = 0; reg < 4; ++reg) {
            int h = hv[reg];
            float v0 = (h == 0) ? acc[rt][0][reg] : (h == 1) ? acc[rt][2][reg]
                     : (h == 2) ? acc[rt][4][reg] : acc[rt][6][reg];
            float v1 = (h == 0) ? acc[rt][1][reg] : (h == 1) ? acc[rt][3][reg]
                     : (h == 2) ? acc[rt][5][reg] : acc[rt][7][reg];
            float s0 = v0 / (1.0f + __expf(-v0));
            float s1 = v1 / (1.0f + __expf(-v1));
            float4v w2a = *(const float4v*)(W2 + (h * 32 + m) * 4);
            float4v w2b = *(const float4v*)(W2 + (h * 32 + 16 + m) * 4);
            float4v o = w2a * s0 + w2b * s1;
            #pragma unroll
            for (int d = 1; d < 16; d <<= 1) {
                o[0] += __shfl_xor(o[0], d, 64);
                o[1] += __shfl_xor(o[1], d, 64);
                o[2] += __shfl_xor(o[2], d, 64);
                o[3] += __shfl_xor(o[3], d, 64);
            }
            if (m == 0) {
                int gr = rowbase + rt * 16 + q * 4 + reg;
                if (gr < nrows) {
                    float4v res = { o[0] * sc, o[1] * sc, o[2] * sc, o[3] * sc };
                    *(float4v*)(out + (size_t)gr * 4) = res;
                }
            }
        }
    }
}

extern "C" void kernel_launch(void* const* d_in, const int* in_sizes, int n_in,
                              void* d_out, int out_size, void* d_ws, size_t ws_size,
                              hipStream_t stream) {
    const float* x     = (const float*)d_in[0];
    const float* W1    = (const float*)d_in[1];
    const float* W2    = (const float*)d_in[2];
    const int*   heads = (const int*)d_in[3];
    float*       out   = (float*)d_out;
    unsigned short* W1p = (unsigned short*)d_ws;   // 64 KB fragment-ordered W1

    int nrows = in_sizes[0] / D_IN;

    prep_w1<<<128, 256, 0, stream>>>(W1, W1p);
    int nb = (nrows + TILE_M - 1) / TILE_M;
    readout_v4<<<nb, 256, 0, stream>>>(x, W1p, W2, heads, out, nrows);
}